// Round 1
// baseline (1731.008 us; speedup 1.0000x reference)
//
#include <hip/hip_runtime.h>

typedef __attribute__((ext_vector_type(8))) _Float16 f16x8;
typedef __attribute__((ext_vector_type(4))) float f32x4;

#define HDIM 128
#define WDIM 128
#define D0 41
#define D1 20
#define D2 9

// ---------------- workspace layout (bytes) ----------------
// X1 [41][128][128][64] f16  (later reused by X3 [20][128][128][64])
#define OFF_X1 0L
#define SZ_X1  (41L*128*128*64*2)          // 85,983,232
// X2 [20][128][128][64] f16  (later reused by X4)
#define OFF_X2 (OFF_X1 + SZ_X1)
#define SZ_X2  (20L*128*128*64*2)          // 41,943,040
// M1 [20][128][128] float
#define OFF_M1 (OFF_X2 + SZ_X2)
#define SZ_M1  (20L*128*128*4)
// weights (f16, [T][CO][CI])
#define OFF_W0 (OFF_M1 + SZ_M1)
#define SZ_W0  (27L*64*128*2)
#define OFF_W1 (OFF_W0 + SZ_W0)
#define SZ_W1  (3L*64*64*2)
#define OFF_W2 (OFF_W1 + SZ_W1)
#define SZ_W2  (27L*64*64*2)
#define OFF_W3 (OFF_W2 + SZ_W2)
#define SZ_W3  (27L*64*64*2)
#define OFF_W4 (OFF_W3 + SZ_W3)
#define SZ_W4  (3L*64*64*2)

// ---------------- weight pre-transform: [CO][CI][T] f32 -> [T][CO][CI] f16 ----
__global__ void prep_w(const float* __restrict__ w, _Float16* __restrict__ o,
                       int CO, int CI, int T) {
    int i = blockIdx.x * 256 + threadIdx.x;
    int n = CO * CI * T;
    if (i >= n) return;
    int t  = i % T;
    int ci = (i / T) % CI;
    int co = i / (T * CI);
    o[((long)t * CO + co) * CI + ci] = (_Float16)w[i];
}

// ---------------- mask downsample: m1 = max over kd of (mask[2d+kd] > .5) ----
__global__ void prep_m1(const float* __restrict__ mask, float* __restrict__ m1) {
    int i = blockIdx.x * 256 + threadIdx.x;
    if (i >= 20 * 16384) return;
    int d1 = i >> 14;
    int rr = i & 16383;
    const float* p = mask + ((long)(2 * d1) << 14) + rr;
    float mx = fmaxf(p[0], fmaxf(p[16384], p[32768]));
    m1[i] = (mx > 0.5f) ? 1.0f : 0.0f;
}

// ---------------- submanifold 3x3x3 conv (SAME), masked output --------------
// CIN=128 FP32_IN=1 : conv0 (reads fp32 NCDHW feat, masks input by mrow>0.5)
// CIN=64  FP32_IN=0 : subm  (reads f16 NDHWC X, no input mask)
// output: relu(conv) * (mrow_out>0.5), f16 NDHWC
template<int CIN, bool FP32_IN>
__global__ __launch_bounds__(128)
void subm_conv(const void* __restrict__ xin,
               const float* __restrict__ mrow,     // [D][128][128] floats
               const _Float16* __restrict__ wt,    // [27][64][CIN]
               _Float16* __restrict__ xout,        // [D][128][128][64]
               int D) {
    const int P = CIN + 8;                         // LDS pitch (f16 elems)
    __shared__ __align__(16) _Float16 lA[130 * (CIN + 8)];
    __shared__ __align__(16) _Float16 lB[64 * (CIN + 8)];
    __shared__ float lM[128];

    const int bid = blockIdx.x;
    const int d = bid >> 7;
    const int h = bid & 127;
    const int tid = threadIdx.x;
    const int wv = tid >> 6;
    const int lane = tid & 63;
    const int q = lane >> 4;
    const int r = lane & 15;

    // output-row mask
    lM[tid] = (mrow[((long)d * 128 + h) * 128 + tid] > 0.5f) ? 1.0f : 0.0f;

    f32x4 acc[4][4];
    #pragma unroll
    for (int mt = 0; mt < 4; ++mt)
        #pragma unroll
        for (int nt = 0; nt < 4; ++nt) {
            acc[mt][nt][0] = 0.f; acc[mt][nt][1] = 0.f;
            acc[mt][nt][2] = 0.f; acc[mt][nt][3] = 0.f;
        }

    const long CS = (long)D * 16384;               // fp32 channel stride (voxels)

    for (int kd = 0; kd < 3; ++kd) {
        int id = d + kd - 1;
        if (id < 0 || id >= D) continue;
        for (int kh = 0; kh < 3; ++kh) {
            int ih = h + kh - 1;
            if (ih < 0 || ih >= 128) continue;
            for (int kw = 0; kw < 3; ++kw) {
                int tap = (kd * 3 + kh) * 3 + kw;
                __syncthreads();                   // prior MFMA done before restage
                if (kw == 0) {
                    // halo voxels v=0 (iw=-1) and v=129 (iw=128) are always OOB: zero
                    {
                        const int nch = P >> 3;    // 16B chunks per row
                        for (int c = tid; c < 2 * nch; c += 128) {
                            int row = (c < nch) ? 0 : 129;
                            int part = (c < nch) ? c : c - nch;
                            f16x8 z;
                            #pragma unroll
                            for (int k = 0; k < 8; ++k) z[k] = (_Float16)0.0f;
                            *(f16x8*)&lA[row * P + part * 8] = z;
                        }
                    }
                    if (FP32_IN) {
                        const float* fsrc = (const float*)xin;
                        long rb = ((long)id * 128 + ih) * 128;
                        int iw = tid;              // 0..127
                        float mval = (mrow[rb + iw] > 0.5f) ? 1.0f : 0.0f;
                        const float* fp = fsrc + rb + iw;
                        for (int ci0 = 0; ci0 < CIN; ci0 += 8) {
                            f16x8 pk;
                            #pragma unroll
                            for (int k = 0; k < 8; ++k)
                                pk[k] = (_Float16)(fp[(long)(ci0 + k) * CS] * mval);
                            *(f16x8*)&lA[(iw + 1) * P + ci0] = pk;
                        }
                    } else {
                        const _Float16* hsrc = (const _Float16*)xin;
                        long rb = (((long)id * 128 + ih) * 128) * CIN;
                        const int nch = CIN >> 3;
                        for (int c = tid; c < 128 * nch; c += 128) {
                            int v = c / nch;
                            int part = c - v * nch;
                            *(f16x8*)&lA[(v + 1) * P + part * 8] =
                                *(const f16x8*)&hsrc[rb + (long)v * CIN + part * 8];
                        }
                    }
                }
                // stage B tap: wt[tap][64][CIN]
                {
                    const _Float16* wsrc = wt + (long)tap * 64 * CIN;
                    const int nch = CIN >> 3;
                    for (int c = tid; c < 64 * nch; c += 128) {
                        int co = c / nch;
                        int part = c - co * nch;
                        *(f16x8*)&lB[co * P + part * 8] =
                            *(const f16x8*)&wsrc[co * CIN + part * 8];
                    }
                }
                __syncthreads();
                // MFMA: wave tile 64 voxels x 64 co
                const int NK = CIN / 32;
                for (int kc = 0; kc < NK; ++kc) {
                    f16x8 af[4], bf[4];
                    #pragma unroll
                    for (int mt = 0; mt < 4; ++mt)
                        af[mt] = *(const f16x8*)&lA[(wv * 64 + mt * 16 + r + kw) * P + kc * 32 + q * 8];
                    #pragma unroll
                    for (int nt = 0; nt < 4; ++nt)
                        bf[nt] = *(const f16x8*)&lB[(nt * 16 + r) * P + kc * 32 + q * 8];
                    #pragma unroll
                    for (int mt = 0; mt < 4; ++mt)
                        #pragma unroll
                        for (int nt = 0; nt < 4; ++nt)
                            acc[mt][nt] = __builtin_amdgcn_mfma_f32_16x16x32_f16(
                                af[mt], bf[nt], acc[mt][nt], 0, 0, 0);
                }
            }
        }
    }
    __syncthreads();
    // epilogue: relu * mask, store NDHWC f16
    long ob = (((long)d * 128 + h) * 128) * 64;
    #pragma unroll
    for (int mt = 0; mt < 4; ++mt) {
        #pragma unroll
        for (int i = 0; i < 4; ++i) {
            int v = wv * 64 + mt * 16 + q * 4 + i;
            float m = lM[v];
            #pragma unroll
            for (int nt = 0; nt < 4; ++nt) {
                float val = acc[mt][nt][i];
                val = val > 0.f ? val : 0.f;
                xout[ob + (long)v * 64 + nt * 16 + r] = (_Float16)(val * m);
            }
        }
    }
}

// ---------------- down1: k=(3,1,1) stride(2,1,1) VALID, relu ----------------
__global__ __launch_bounds__(128)
void down1_kernel(const _Float16* __restrict__ xin,  // X1 [41][128][128][64]
                  const _Float16* __restrict__ wt,   // [3][64][64]
                  _Float16* __restrict__ xout) {     // X2 [20][128][128][64]
    __shared__ __align__(16) _Float16 lB[3 * 64 * 72];
    const int bid = blockIdx.x;
    const int d1 = bid >> 7;
    const int h = bid & 127;
    const int tid = threadIdx.x;
    const int wv = tid >> 6;
    const int lane = tid & 63;
    const int q = lane >> 4;
    const int r = lane & 15;

    for (int c = tid; c < 3 * 64 * 8; c += 128) {
        int row = c >> 3;                    // kd*64+co
        int part = c & 7;
        *(f16x8*)&lB[row * 72 + part * 8] = *(const f16x8*)&wt[row * 64 + part * 8];
    }
    __syncthreads();

    f32x4 acc[4][4];
    #pragma unroll
    for (int mt = 0; mt < 4; ++mt)
        #pragma unroll
        for (int nt = 0; nt < 4; ++nt) {
            acc[mt][nt][0] = 0.f; acc[mt][nt][1] = 0.f;
            acc[mt][nt][2] = 0.f; acc[mt][nt][3] = 0.f;
        }

    for (int kd = 0; kd < 3; ++kd) {
        long ib = (((long)(2 * d1 + kd) * 128 + h) * 128) * 64;
        for (int kc = 0; kc < 2; ++kc) {
            f16x8 af[4], bf[4];
            #pragma unroll
            for (int mt = 0; mt < 4; ++mt)
                af[mt] = *(const f16x8*)&xin[ib + (long)(wv * 64 + mt * 16 + r) * 64 + kc * 32 + q * 8];
            #pragma unroll
            for (int nt = 0; nt < 4; ++nt)
                bf[nt] = *(const f16x8*)&lB[(kd * 64 + nt * 16 + r) * 72 + kc * 32 + q * 8];
            #pragma unroll
            for (int mt = 0; mt < 4; ++mt)
                #pragma unroll
                for (int nt = 0; nt < 4; ++nt)
                    acc[mt][nt] = __builtin_amdgcn_mfma_f32_16x16x32_f16(
                        af[mt], bf[nt], acc[mt][nt], 0, 0, 0);
        }
    }
    long ob = (((long)d1 * 128 + h) * 128) * 64;
    #pragma unroll
    for (int mt = 0; mt < 4; ++mt)
        #pragma unroll
        for (int i = 0; i < 4; ++i) {
            int v = wv * 64 + mt * 16 + q * 4 + i;
            #pragma unroll
            for (int nt = 0; nt < 4; ++nt) {
                float val = acc[mt][nt][i];
                xout[ob + (long)v * 64 + nt * 16 + r] = (_Float16)(val > 0.f ? val : 0.f);
            }
        }
}

// ---------------- down2: k=(3,1,1) stride(2,1,1), relu, fp32 NCDHW out ------
// swapped-operand MFMA: D[m=co][n=voxel] -> coalesced NCDHW stores
__global__ __launch_bounds__(128)
void down2_kernel(const _Float16* __restrict__ xin,  // X4 [20][128][128][64]
                  const _Float16* __restrict__ wt,   // [3][64][64]
                  float* __restrict__ out) {         // [64][9][128][128]
    __shared__ __align__(16) _Float16 lB[3 * 64 * 72];
    const int bid = blockIdx.x;
    const int d2 = bid >> 7;
    const int h = bid & 127;
    const int tid = threadIdx.x;
    const int wv = tid >> 6;
    const int lane = tid & 63;
    const int q = lane >> 4;
    const int r = lane & 15;

    for (int c = tid; c < 3 * 64 * 8; c += 128) {
        int row = c >> 3;
        int part = c & 7;
        *(f16x8*)&lB[row * 72 + part * 8] = *(const f16x8*)&wt[row * 64 + part * 8];
    }
    __syncthreads();

    f32x4 acc[4][4];   // [mt=co tile][nt=voxel tile]
    #pragma unroll
    for (int mt = 0; mt < 4; ++mt)
        #pragma unroll
        for (int nt = 0; nt < 4; ++nt) {
            acc[mt][nt][0] = 0.f; acc[mt][nt][1] = 0.f;
            acc[mt][nt][2] = 0.f; acc[mt][nt][3] = 0.f;
        }

    for (int kd = 0; kd < 3; ++kd) {
        long ib = (((long)(2 * d2 + kd) * 128 + h) * 128) * 64;
        for (int kc = 0; kc < 2; ++kc) {
            f16x8 wf[4], xf[4];
            #pragma unroll
            for (int mt = 0; mt < 4; ++mt)
                wf[mt] = *(const f16x8*)&lB[(kd * 64 + mt * 16 + r) * 72 + kc * 32 + q * 8];
            #pragma unroll
            for (int nt = 0; nt < 4; ++nt)
                xf[nt] = *(const f16x8*)&xin[ib + (long)(wv * 64 + nt * 16 + r) * 64 + kc * 32 + q * 8];
            #pragma unroll
            for (int mt = 0; mt < 4; ++mt)
                #pragma unroll
                for (int nt = 0; nt < 4; ++nt)
                    acc[mt][nt] = __builtin_amdgcn_mfma_f32_16x16x32_f16(
                        wf[mt], xf[nt], acc[mt][nt], 0, 0, 0);
        }
    }
    #pragma unroll
    for (int mt = 0; mt < 4; ++mt)
        #pragma unroll
        for (int i = 0; i < 4; ++i) {
            int co = mt * 16 + q * 4 + i;
            #pragma unroll
            for (int nt = 0; nt < 4; ++nt) {
                int v = wv * 64 + nt * 16 + r;
                float val = acc[mt][nt][i];
                out[((long)co * 9 + d2) * 16384 + h * 128 + v] = (val > 0.f ? val : 0.f);
            }
        }
}

// ---------------- launcher ----------------
extern "C" void kernel_launch(void* const* d_in, const int* in_sizes, int n_in,
                              void* d_out, int out_size, void* d_ws, size_t ws_size,
                              hipStream_t stream) {
    (void)in_sizes; (void)n_in; (void)out_size; (void)ws_size;
    const float* feat = (const float*)d_in[0];
    const float* mask = (const float*)d_in[1];
    const float* w0 = (const float*)d_in[2];
    const float* w1 = (const float*)d_in[3];
    const float* w2 = (const float*)d_in[4];
    const float* w3 = (const float*)d_in[5];
    const float* w4 = (const float*)d_in[6];

    char* ws = (char*)d_ws;
    _Float16* X1  = (_Float16*)(ws + OFF_X1);
    _Float16* X2  = (_Float16*)(ws + OFF_X2);
    _Float16* X3  = (_Float16*)(ws + OFF_X1);   // reuse X1 region
    _Float16* X4  = (_Float16*)(ws + OFF_X2);   // reuse X2 region
    float*    M1  = (float*)(ws + OFF_M1);
    _Float16* W0t = (_Float16*)(ws + OFF_W0);
    _Float16* W1t = (_Float16*)(ws + OFF_W1);
    _Float16* W2t = (_Float16*)(ws + OFF_W2);
    _Float16* W3t = (_Float16*)(ws + OFF_W3);
    _Float16* W4t = (_Float16*)(ws + OFF_W4);

    prep_w<<<(27*64*128 + 255) / 256, 256, 0, stream>>>(w0, W0t, 64, 128, 27);
    prep_w<<<(3*64*64   + 255) / 256, 256, 0, stream>>>(w1, W1t, 64, 64, 3);
    prep_w<<<(27*64*64  + 255) / 256, 256, 0, stream>>>(w2, W2t, 64, 64, 27);
    prep_w<<<(27*64*64  + 255) / 256, 256, 0, stream>>>(w3, W3t, 64, 64, 27);
    prep_w<<<(3*64*64   + 255) / 256, 256, 0, stream>>>(w4, W4t, 64, 64, 3);
    prep_m1<<<(20*16384 + 255) / 256, 256, 0, stream>>>(mask, M1);

    // conv0: 128->64, 3x3x3 SAME, masked in & out
    subm_conv<128, true><<<41 * 128, 128, 0, stream>>>(feat, mask, W0t, X1, 41);
    // down1: 64->64, (3,1,1)/(2,1,1) VALID, relu
    down1_kernel<<<20 * 128, 128, 0, stream>>>(X1, W1t, X2);
    // subm1a / subm1b: 64->64, 3x3x3 SAME, masked out (mask M1)
    subm_conv<64, false><<<20 * 128, 128, 0, stream>>>(X2, M1, W2t, X3, 20);
    subm_conv<64, false><<<20 * 128, 128, 0, stream>>>(X3, M1, W3t, X4, 20);
    // down2 -> fp32 NCDHW output
    down2_kernel<<<9 * 128, 128, 0, stream>>>(X4, W4t, (float*)d_out);
}